// Round 11
// baseline (175.376 us; speedup 1.0000x reference)
//
#include <hip/hip_runtime.h>
#include <hip/hip_cooperative_groups.h>
#include <math.h>

#define D 256          // feature dim (fixed by reference)
#define NREL 16        // relation count
#define CHUNK 6250     // nodes per dst-chunk (2 x f32 LDS arrays = 50 KB)
#define NSL 64         // edge slices per chunk (coop path)
#define BPC 32         // slices per chunk (fallback path)
#define NBLK 512       // cooperative grid: 2 blocks/CU x 256 CU
#define NTHR 512

namespace cg = cooperative_groups;

typedef float f4v __attribute__((ext_vector_type(4)));

// ---------------------------------------------------------------------------
// Fused cooperative kernel: phase A (y = x*W, xr = x*root) -> grid.sync ->
// phase B (chunked edge scan, LDS accumulate, partial flush) -> grid.sync ->
// phase C (reduce partials + tanh + scale x).
// 64 KB LDS union: A uses 64x256 swizzled tile, B uses 6250x(sum,cnt),
// C uses 192 floats.
// ---------------------------------------------------------------------------
__global__ __launch_bounds__(NTHR, 4) void rgcn_fused_kernel(
    const float* __restrict__ x, const int* __restrict__ src,
    const int* __restrict__ dst, const int* __restrict__ et,
    const float* __restrict__ w, const float* __restrict__ root,
    const float* __restrict__ bias, float* __restrict__ y,
    float* __restrict__ xr, float2* __restrict__ partial,
    float* __restrict__ out_x, float* __restrict__ out_score,
    int n, int e, int sl)
{
    cg::grid_group grid = cg::this_grid();
    __shared__ float lds[D * 64];     // 64 KB
    const int t   = threadIdx.x;
    const int bid = blockIdx.x;
    const int ntiles = (n + 63) / 64;
    const int C = (n + CHUNK - 1) / CHUNK;

    // ================= Phase A =================
    for (int tile = bid; tile < ntiles; tile += NBLK) {
        const int base = tile * 64;
        const int nl  = t & 63;
        const int rg  = __builtin_amdgcn_readfirstlane(t >> 6);  // 0..7
        const int f4i = t & 63;

        #pragma unroll
        for (int k = 0; k < 8; ++k) {
            int snl = k * 8 + (t >> 6);   // wave-uniform row
            int gn  = base + snl;
            float4 v = make_float4(0.f, 0.f, 0.f, 0.f);
            if (gn < n)
                v = *reinterpret_cast<const float4*>(x + (size_t)gn * D + f4i * 4);
            int rsw = (snl + f4i) & 63;   // swizzled row slot
            lds[(f4i * 4 + 0) * 64 + rsw] = v.x;
            lds[(f4i * 4 + 1) * 64 + rsw] = v.y;
            lds[(f4i * 4 + 2) * 64 + rsw] = v.z;
            lds[(f4i * 4 + 3) * 64 + rsw] = v.w;
        }
        __syncthreads();

        const float* w0 = w + (size_t)(rg * 2 + 0) * D;
        const float* w1 = w + (size_t)(rg * 2 + 1) * D;
        float a0 = 0.f, a1 = 0.f, aR = 0.f;
        if (rg < 7) {
            #pragma unroll 8
            for (int q = 0; q < 64; ++q) {
                int rs = (nl + q) & 63;
                #pragma unroll
                for (int j = 0; j < 4; ++j) {
                    int d = q * 4 + j;
                    float xv = lds[d * 64 + rs];
                    a0 = fmaf(xv, w0[d], a0);
                    a1 = fmaf(xv, w1[d], a1);
                }
            }
        } else {
            #pragma unroll 8
            for (int q = 0; q < 64; ++q) {
                int rs = (nl + q) & 63;
                #pragma unroll
                for (int j = 0; j < 4; ++j) {
                    int d = q * 4 + j;
                    float xv = lds[d * 64 + rs];
                    a0 = fmaf(xv, w0[d], a0);
                    a1 = fmaf(xv, w1[d], a1);
                    aR = fmaf(xv, root[d], aR);
                }
            }
        }
        int node = base + nl;
        if (node < n) {
            float2 o; o.x = a0; o.y = a1;
            *reinterpret_cast<float2*>(y + (size_t)node * NREL + rg * 2) = o;
            if (rg == 7) xr[node] = aR;
        }
        __syncthreads();   // LDS reuse across tiles
    }
    grid.sync();

    // ================= Phase B: edge scan =================
    {
        float* lsum = lds;
        float* lcnt = lds + CHUNK;
        for (int sb = bid; sb < C * NSL; sb += NBLK) {
            const int c = sb / NSL;
            const int s = sb % NSL;
            const int base = c * CHUNK;
            for (int j = t; j < CHUNK; j += NTHR) { lsum[j] = 0.f; lcnt[j] = 0.f; }
            __syncthreads();

            const int slice0 = s * sl;
            const int rem = e - slice0;
            if (rem > 0) {
                const int gmax = (min(sl, rem) + 3) >> 2;
                for (int g = t; g < gmax; g += NTHR) {
                    int idx = slice0 + g * 4;
                    if (idx + 3 < e) {
                        int4 d4 = *reinterpret_cast<const int4*>(dst + idx);
                        int4 s4 = *reinterpret_cast<const int4*>(src + idx);
                        int4 r4 = *reinterpret_cast<const int4*>(et + idx);
                        int loc0 = d4.x - base, loc1 = d4.y - base;
                        int loc2 = d4.z - base, loc3 = d4.w - base;
                        if ((unsigned)loc0 < (unsigned)CHUNK) {
                            atomicAdd(&lsum[loc0], y[(size_t)s4.x * NREL + r4.x]);
                            atomicAdd(&lcnt[loc0], 1.0f);
                        }
                        if ((unsigned)loc1 < (unsigned)CHUNK) {
                            atomicAdd(&lsum[loc1], y[(size_t)s4.y * NREL + r4.y]);
                            atomicAdd(&lcnt[loc1], 1.0f);
                        }
                        if ((unsigned)loc2 < (unsigned)CHUNK) {
                            atomicAdd(&lsum[loc2], y[(size_t)s4.z * NREL + r4.z]);
                            atomicAdd(&lcnt[loc2], 1.0f);
                        }
                        if ((unsigned)loc3 < (unsigned)CHUNK) {
                            atomicAdd(&lsum[loc3], y[(size_t)s4.w * NREL + r4.w]);
                            atomicAdd(&lcnt[loc3], 1.0f);
                        }
                    } else {
                        for (int k = idx; k < e && k < idx + 4; ++k) {
                            int loc = dst[k] - base;
                            if ((unsigned)loc < (unsigned)CHUNK) {
                                atomicAdd(&lsum[loc], y[(size_t)src[k] * NREL + et[k]]);
                                atomicAdd(&lcnt[loc], 1.0f);
                            }
                        }
                    }
                }
            }
            __syncthreads();

            float2* p = partial + (size_t)sb * CHUNK;
            for (int j = t; j < CHUNK; j += NTHR)
                p[j] = make_float2(lsum[j], lcnt[j]);
            __syncthreads();
        }
    }
    grid.sync();

    // ================= Phase C: reduce + score + scale =================
    {
        float* ssum = lds;
        float* scnt = lds + 64;
        float* sc   = lds + 128;
        for (int tile = bid; tile < ntiles; tile += NBLK) {
            const int base = tile * 64;
            if (t < 128) lds[t] = 0.f;
            __syncthreads();
            {
                int nl = t & 63;
                int bg = t >> 6;            // 0..7 -> 8 partials each
                int node = base + nl;
                float s_ = 0.f, cN = 0.f;
                if (node < n) {
                    int c = node / CHUNK;
                    int j = node - c * CHUNK;
                    const float2* p = partial + (size_t)c * NSL * CHUNK + j;
                    #pragma unroll
                    for (int b = 0; b < 8; ++b) {
                        float2 v = p[(size_t)(bg * 8 + b) * CHUNK];
                        s_ += v.x; cN += v.y;
                    }
                }
                atomicAdd(&ssum[nl], s_);
                atomicAdd(&scnt[nl], cN);
            }
            __syncthreads();
            if (t < 64) {
                int node = base + t;
                if (node < n) {
                    float m = ssum[t] / fmaxf(scnt[t], 1.0f);
                    float v = tanhf(m + xr[node] + bias[0]);
                    sc[t] = v;
                    out_score[node] = v;
                }
            }
            __syncthreads();
            #pragma unroll
            for (int k = 0; k < 8; ++k) {
                int flat = k * NTHR + t;    // 0..4095
                int nl = flat >> 6;
                int f4 = flat & 63;
                int node = base + nl;
                if (node < n) {
                    float s_ = sc[nl];
                    float4 v = *reinterpret_cast<const float4*>(
                                   x + (size_t)node * D + f4 * 4);
                    v.x *= s_; v.y *= s_; v.z *= s_; v.w *= s_;
                    f4v vo = {v.x, v.y, v.z, v.w};
                    __builtin_nontemporal_store(
                        vo, (f4v*)(out_x + (size_t)node * D + f4 * 4));
                }
            }
            __syncthreads();
        }
    }
}

// ======================= fallback path (proven 4-kernel) ====================
__global__ __launch_bounds__(512) void rgcn_y_kernel(
    const float* __restrict__ x, const float* __restrict__ w,
    const float* __restrict__ root, float* __restrict__ y,
    float* __restrict__ xr, int n)
{
    __shared__ float lds[D * 64];
    const int t    = threadIdx.x;
    const int nl   = t & 63;
    const int rg   = __builtin_amdgcn_readfirstlane(t >> 6);
    const int base = blockIdx.x * 64;
    const int node = base + nl;

    const int f4i = t & 63;
    #pragma unroll
    for (int k = 0; k < 8; ++k) {
        int snl = k * 8 + (t >> 6);
        int gn  = base + snl;
        float4 v = make_float4(0.f, 0.f, 0.f, 0.f);
        if (gn < n)
            v = *reinterpret_cast<const float4*>(x + (size_t)gn * D + f4i * 4);
        int rsw = (snl + f4i) & 63;
        lds[(f4i * 4 + 0) * 64 + rsw] = v.x;
        lds[(f4i * 4 + 1) * 64 + rsw] = v.y;
        lds[(f4i * 4 + 2) * 64 + rsw] = v.z;
        lds[(f4i * 4 + 3) * 64 + rsw] = v.w;
    }
    __syncthreads();

    const float* w0 = w + (size_t)(rg * 2 + 0) * D;
    const float* w1 = w + (size_t)(rg * 2 + 1) * D;
    float a0 = 0.f, a1 = 0.f, aR = 0.f;
    #pragma unroll 8
    for (int q = 0; q < 64; ++q) {
        int rs = (nl + q) & 63;
        #pragma unroll
        for (int j = 0; j < 4; ++j) {
            int d = q * 4 + j;
            float xv = lds[d * 64 + rs];
            a0 = fmaf(xv, w0[d], a0);
            a1 = fmaf(xv, w1[d], a1);
            if (rg == 7) aR = fmaf(xv, root[d], aR);
        }
    }
    if (node < n) {
        float2 o; o.x = a0; o.y = a1;
        *reinterpret_cast<float2*>(y + (size_t)node * NREL + rg * 2) = o;
        if (rg == 7) xr[node] = aR;
    }
}

__global__ __launch_bounds__(1024) void rgcn_edge_scan_kernel(
    const int* __restrict__ src, const int* __restrict__ dst,
    const int* __restrict__ et, const float* __restrict__ y,
    float2* __restrict__ partial, int e, int sl)
{
    __shared__ float lsum[CHUNK];
    __shared__ float lcnt[CHUNK];
    const int t = threadIdx.x;
    const int c = blockIdx.x / BPC;
    const int b = blockIdx.x % BPC;
    const int base = c * CHUNK;

    for (int j = t; j < CHUNK; j += 1024) { lsum[j] = 0.f; lcnt[j] = 0.f; }
    __syncthreads();

    const int slice0 = b * sl;
    const int rem = e - slice0;
    if (rem > 0) {
        const int gmax = (min(sl, rem) + 3) >> 2;
        for (int g = t; g < gmax; g += 1024) {
            int idx = slice0 + g * 4;
            if (idx + 3 < e) {
                int4 d4 = *reinterpret_cast<const int4*>(dst + idx);
                int4 s4 = *reinterpret_cast<const int4*>(src + idx);
                int4 r4 = *reinterpret_cast<const int4*>(et + idx);
                int loc0 = d4.x - base, loc1 = d4.y - base;
                int loc2 = d4.z - base, loc3 = d4.w - base;
                if ((unsigned)loc0 < (unsigned)CHUNK) {
                    atomicAdd(&lsum[loc0], y[(size_t)s4.x * NREL + r4.x]);
                    atomicAdd(&lcnt[loc0], 1.0f);
                }
                if ((unsigned)loc1 < (unsigned)CHUNK) {
                    atomicAdd(&lsum[loc1], y[(size_t)s4.y * NREL + r4.y]);
                    atomicAdd(&lcnt[loc1], 1.0f);
                }
                if ((unsigned)loc2 < (unsigned)CHUNK) {
                    atomicAdd(&lsum[loc2], y[(size_t)s4.z * NREL + r4.z]);
                    atomicAdd(&lcnt[loc2], 1.0f);
                }
                if ((unsigned)loc3 < (unsigned)CHUNK) {
                    atomicAdd(&lsum[loc3], y[(size_t)s4.w * NREL + r4.w]);
                    atomicAdd(&lcnt[loc3], 1.0f);
                }
            } else {
                for (int k = idx; k < e && k < idx + 4; ++k) {
                    int loc = dst[k] - base;
                    if ((unsigned)loc < (unsigned)CHUNK) {
                        atomicAdd(&lsum[loc], y[(size_t)src[k] * NREL + et[k]]);
                        atomicAdd(&lcnt[loc], 1.0f);
                    }
                }
            }
        }
    }
    __syncthreads();

    float2* p = partial + ((size_t)(c * BPC + b)) * CHUNK;
    for (int j = t; j < CHUNK; j += 1024)
        p[j] = make_float2(lsum[j], lcnt[j]);
}

__global__ __launch_bounds__(256) void rgcn_finish_kernel(
    const float2* __restrict__ partial, const float* __restrict__ xr,
    const float* __restrict__ bias, const float* __restrict__ x,
    float* __restrict__ out_x, float* __restrict__ out_score, int n)
{
    __shared__ float ssum[32], scnt[32], sc[32];
    const int t = threadIdx.x;
    const int base = blockIdx.x * 32;

    if (t < 32) { ssum[t] = 0.f; scnt[t] = 0.f; }
    __syncthreads();
    {
        int nl = t & 31;
        int bg = t >> 5;
        int node = base + nl;
        float s = 0.f, cN = 0.f;
        if (node < n) {
            int c = node / CHUNK;
            int j = node - c * CHUNK;
            const float2* p = partial + (size_t)c * BPC * CHUNK + j;
            #pragma unroll
            for (int b = 0; b < 4; ++b) {
                float2 v = p[(size_t)(bg * 4 + b) * CHUNK];
                s += v.x; cN += v.y;
            }
        }
        atomicAdd(&ssum[nl], s);
        atomicAdd(&scnt[nl], cN);
    }
    __syncthreads();
    if (t < 32) {
        int node = base + t;
        if (node < n) {
            float m = ssum[t] / fmaxf(scnt[t], 1.0f);
            float v = tanhf(m + xr[node] + bias[0]);
            sc[t] = v;
            out_score[node] = v;
        }
    }
    __syncthreads();
    #pragma unroll
    for (int k = 0; k < 8; ++k) {
        int nl = k * 4 + (t >> 6);
        int f4 = t & 63;
        int node = base + nl;
        if (node < n) {
            float s = sc[nl];
            float4 v = *reinterpret_cast<const float4*>(
                           x + (size_t)node * D + f4 * 4);
            v.x *= s; v.y *= s; v.z *= s; v.w *= s;
            f4v vo = {v.x, v.y, v.z, v.w};
            __builtin_nontemporal_store(
                vo, (f4v*)(out_x + (size_t)node * D + f4 * 4));
        }
    }
}

__global__ __launch_bounds__(256) void rgcn_reduce_score_kernel(
    const float2* __restrict__ partial, const float* __restrict__ xr,
    const float* __restrict__ bias, float* __restrict__ score, int n)
{
    int i = blockIdx.x * 256 + threadIdx.x;
    if (i < n) {
        int c = i / CHUNK;
        int j = i - c * CHUNK;
        const float2* p = partial + (size_t)c * BPC * CHUNK + j;
        float s = 0.f, cN = 0.f;
        #pragma unroll 8
        for (int b = 0; b < BPC; ++b) {
            float2 v = p[(size_t)b * CHUNK];
            s += v.x; cN += v.y;
        }
        float m = s / fmaxf(cN, 1.0f);
        score[i] = tanhf(m + xr[i] + bias[0]);
    }
}

__global__ __launch_bounds__(256) void rgcn_scale_kernel(
    const float* __restrict__ x, const float* __restrict__ score,
    float* __restrict__ xo, int n)
{
    int gid = blockIdx.x * 256 + threadIdx.x;
    int node = gid >> 6;
    int f4 = gid & 63;
    if (node < n) {
        float s = score[node];
        float4 v = *reinterpret_cast<const float4*>(
                       x + (size_t)node * D + f4 * 4);
        v.x *= s; v.y *= s; v.z *= s; v.w *= s;
        *reinterpret_cast<float4*>(xo + (size_t)node * D + f4 * 4) = v;
    }
}

extern "C" void kernel_launch(void* const* d_in, const int* in_sizes, int n_in,
                              void* d_out, int out_size, void* d_ws, size_t ws_size,
                              hipStream_t stream)
{
    const float* x    = (const float*)d_in[0];
    const int*   ei   = (const int*)d_in[1];   // (2, E): src then dst
    const int*   et   = (const int*)d_in[2];
    const float* w    = (const float*)d_in[3];
    const float* root = (const float*)d_in[4];
    const float* bias = (const float*)d_in[5];

    int n = in_sizes[0] / D;   // 50000
    int e = in_sizes[2];       // 800000

    float* out       = (float*)d_out;
    float* out_x     = out;
    float* out_score = out + (size_t)n * D;

    const int C = (n + CHUNK - 1) / CHUNK;               // 8
    int sl64 = ((((e + NSL - 1) / NSL) + 3) & ~3);       // coop slice len
    const int sl32 = ((((e + BPC - 1) / BPC) + 3) & ~3); // fallback slice len

    // Scratch: partials (C*NSL*CHUNK float2, superset of fallback's C*BPC) |
    //          y (16n) | xr (n)
    const size_t part_f = (size_t)C * NSL * CHUNK * 2;
    const size_t need_f = part_f + (size_t)n * (NREL + 1);
    const bool use_ws = (ws_size >= need_f * sizeof(float));

    float* sb;
    if (use_ws)
        sb = (float*)d_ws;
    else {
        size_t ts = (((size_t)n * D - need_f) & ~(size_t)1);
        sb = out_x + ts;
    }
    float2* partial = (float2*)sb;
    float*  y  = sb + part_f;
    float*  xr = y + (size_t)n * NREL;

    bool coop_done = false;
    if (use_ws) {
        const int* srcp = ei;
        const int* dstp = ei + e;
        void* args[] = {
            (void*)&x, (void*)&srcp, (void*)&dstp, (void*)&et,
            (void*)&w, (void*)&root, (void*)&bias, (void*)&y,
            (void*)&xr, (void*)&partial, (void*)&out_x, (void*)&out_score,
            (void*)&n, (void*)&e, (void*)&sl64 };
        hipError_t err = hipLaunchCooperativeKernel(
            (void*)rgcn_fused_kernel, dim3(NBLK), dim3(NTHR), args, 0, stream);
        coop_done = (err == hipSuccess);
    }

    if (!coop_done) {
        rgcn_y_kernel<<<dim3((n + 63) / 64), dim3(512), 0, stream>>>(
            x, w, root, y, xr, n);
        rgcn_edge_scan_kernel<<<dim3(C * BPC), dim3(1024), 0, stream>>>(
            ei, ei + e, et, y, partial, e, sl32);
        if (use_ws) {
            rgcn_finish_kernel<<<dim3((n + 31) / 32), dim3(256), 0, stream>>>(
                partial, xr, bias, x, out_x, out_score, n);
        } else {
            rgcn_reduce_score_kernel<<<dim3((n + 255) / 256), dim3(256), 0, stream>>>(
                partial, xr, bias, out_score, n);
            rgcn_scale_kernel<<<dim3((int)(((size_t)n * 64 + 255) / 256)), dim3(256), 0, stream>>>(
                x, out_score, out_x, n);
        }
    }
}

// Round 12
// 66.020 us; speedup vs baseline: 2.6564x; 2.6564x over previous
//
#include <hip/hip_runtime.h>
#include <math.h>

#define D 256          // feature dim (fixed by reference)
#define NREL 16        // relation count
#define CHUNK 6250     // nodes per dst-chunk (2 x f32 LDS arrays = 50 KB)
#define BPC 32         // blocks per chunk (edge-slice parallelism)
#define LDST8 132      // LDS row stride: 528 B (16B-aligned rows, 2-way banks = free)

typedef float f4v __attribute__((ext_vector_type(4)));

// ---------------------------------------------------------------------------
// Kernel A v8: y[n][r] = dot(x[n], W[r]) r<16, xr[n] = dot(x[n], root).
// v4 two-half structure, but LDS tile is [64][132] so every thread reads its
// node's row via ds_read_b128 (64 vector reads/thread instead of 256 b32).
// Bank math: word = 132*nl + 4*dq + j -> bank 4(nl+dq)+j mod 32: within each
// 16-lane phase exactly 2 lanes/bank = free (m136). Writes are b128, aligned.
// rg = t>>6 owns 4 W rows (wave-uniform -> scalar loads); rg 3 adds root.
// ---------------------------------------------------------------------------
__global__ __launch_bounds__(256) void rgcn_y_kernel(
    const float* __restrict__ x, const float* __restrict__ w,
    const float* __restrict__ root, float* __restrict__ y,
    float* __restrict__ xr, int n)
{
    __shared__ float lds[64 * LDST8];   // 33.8 KB -> 4 blocks/CU
    const int t = threadIdx.x;
    const int nl = t & 63;
    const int rg = __builtin_amdgcn_readfirstlane(t >> 6);  // wave-uniform
    const int base = blockIdx.x * 64;
    const int node = base + nl;

    const float* w0 = w + (size_t)(rg * 4 + 0) * D;
    const float* w1 = w + (size_t)(rg * 4 + 1) * D;
    const float* w2 = w + (size_t)(rg * 4 + 2) * D;
    const float* w3 = w + (size_t)(rg * 4 + 3) * D;
    const float* w4 = (rg == 3) ? root : w0;  // root handled by rgroup 3

    float a0 = 0.f, a1 = 0.f, a2 = 0.f, a3 = 0.f, aR = 0.f;

    #pragma unroll
    for (int h = 0; h < 2; ++h) {   // two 128-d halves
        // ---- stage 64 nodes x 128 d: 8 independent float4 loads/thread ----
        #pragma unroll
        for (int k = 0; k < 8; ++k) {
            int flat = k * 256 + t;       // float4 slot 0..2047
            int snl  = flat >> 5;         // staged node local 0..63
            int c16  = flat & 31;         // float4 idx within 128-d half
            int gn   = base + snl;
            float4 v = make_float4(0.f, 0.f, 0.f, 0.f);
            if (gn < n)
                v = *reinterpret_cast<const float4*>(
                        x + (size_t)gn * D + h * 128 + c16 * 4);
            *reinterpret_cast<float4*>(&lds[snl * LDST8 + c16 * 4]) = v;
        }
        __syncthreads();

        const float* h0 = w0 + h * 128;
        const float* h1 = w1 + h * 128;
        const float* h2 = w2 + h * 128;
        const float* h3 = w3 + h * 128;
        const float* h4 = w4 + h * 128;
        #pragma unroll 8
        for (int dq = 0; dq < 32; ++dq) {
            float4 xv = *reinterpret_cast<const float4*>(
                            &lds[nl * LDST8 + dq * 4]);      // ds_read_b128
            const int d = dq * 4;
            a0 = fmaf(xv.x, h0[d+0], a0); a0 = fmaf(xv.y, h0[d+1], a0);
            a0 = fmaf(xv.z, h0[d+2], a0); a0 = fmaf(xv.w, h0[d+3], a0);
            a1 = fmaf(xv.x, h1[d+0], a1); a1 = fmaf(xv.y, h1[d+1], a1);
            a1 = fmaf(xv.z, h1[d+2], a1); a1 = fmaf(xv.w, h1[d+3], a1);
            a2 = fmaf(xv.x, h2[d+0], a2); a2 = fmaf(xv.y, h2[d+1], a2);
            a2 = fmaf(xv.z, h2[d+2], a2); a2 = fmaf(xv.w, h2[d+3], a2);
            a3 = fmaf(xv.x, h3[d+0], a3); a3 = fmaf(xv.y, h3[d+1], a3);
            a3 = fmaf(xv.z, h3[d+2], a3); a3 = fmaf(xv.w, h3[d+3], a3);
            aR = fmaf(xv.x, h4[d+0], aR); aR = fmaf(xv.y, h4[d+1], aR);
            aR = fmaf(xv.z, h4[d+2], aR); aR = fmaf(xv.w, h4[d+3], aR);
        }
        if (h == 0) __syncthreads();   // tile reuse barrier
    }

    if (node < n) {
        float4 o; o.x = a0; o.y = a1; o.z = a2; o.w = a3;
        *reinterpret_cast<float4*>(y + (size_t)node * NREL + rg * 4) = o;
        if (rg == 3) xr[node] = aR;
    }
}

// ---------------------------------------------------------------------------
// Kernel B: chunked edge scan, LDS accumulation, zero global atomics.
// Unconditional int4 loads of dst/src/et (3 independent vector loads per
// 4-edge group -> deep memory-level parallelism).
// ---------------------------------------------------------------------------
__global__ __launch_bounds__(1024) void rgcn_edge_scan_kernel(
    const int* __restrict__ src, const int* __restrict__ dst,
    const int* __restrict__ et, const float* __restrict__ y,
    float2* __restrict__ partial, int e, int sl)
{
    __shared__ float lsum[CHUNK];
    __shared__ float lcnt[CHUNK];
    const int t = threadIdx.x;
    const int c = blockIdx.x / BPC;
    const int b = blockIdx.x % BPC;
    const int base = c * CHUNK;

    for (int j = t; j < CHUNK; j += 1024) { lsum[j] = 0.f; lcnt[j] = 0.f; }
    __syncthreads();

    const int slice0 = b * sl;
    const int rem = e - slice0;
    if (rem > 0) {
        const int gmax = (min(sl, rem) + 3) >> 2;   // int4 groups in slice
        for (int g = t; g < gmax; g += 1024) {
            int idx = slice0 + g * 4;
            if (idx + 3 < e) {
                int4 d4 = *reinterpret_cast<const int4*>(dst + idx);
                int4 s4 = *reinterpret_cast<const int4*>(src + idx);
                int4 r4 = *reinterpret_cast<const int4*>(et + idx);
                int loc0 = d4.x - base, loc1 = d4.y - base;
                int loc2 = d4.z - base, loc3 = d4.w - base;
                if ((unsigned)loc0 < (unsigned)CHUNK) {
                    atomicAdd(&lsum[loc0], y[(size_t)s4.x * NREL + r4.x]);
                    atomicAdd(&lcnt[loc0], 1.0f);
                }
                if ((unsigned)loc1 < (unsigned)CHUNK) {
                    atomicAdd(&lsum[loc1], y[(size_t)s4.y * NREL + r4.y]);
                    atomicAdd(&lcnt[loc1], 1.0f);
                }
                if ((unsigned)loc2 < (unsigned)CHUNK) {
                    atomicAdd(&lsum[loc2], y[(size_t)s4.z * NREL + r4.z]);
                    atomicAdd(&lcnt[loc2], 1.0f);
                }
                if ((unsigned)loc3 < (unsigned)CHUNK) {
                    atomicAdd(&lsum[loc3], y[(size_t)s4.w * NREL + r4.w]);
                    atomicAdd(&lcnt[loc3], 1.0f);
                }
            } else {
                for (int k = idx; k < e && k < idx + 4; ++k) {
                    int loc = dst[k] - base;
                    if ((unsigned)loc < (unsigned)CHUNK) {
                        atomicAdd(&lsum[loc], y[(size_t)src[k] * NREL + et[k]]);
                        atomicAdd(&lcnt[loc], 1.0f);
                    }
                }
            }
        }
    }
    __syncthreads();

    float2* p = partial + ((size_t)(c * BPC + b)) * CHUNK;
    for (int j = t; j < CHUNK; j += 1024)
        p[j] = make_float2(lsum[j], lcnt[j]);
}

// ---------------------------------------------------------------------------
// Kernel C (fused finish), 32 nodes/block:
//   phase 1 (ALL threads): thread t reduces 4 partials of node t&31
//                          (b-group t>>5), LDS-atomic combine;
//                          then 32 threads do tanh -> sc[] + out_score.
//   phase 2 (all):  x_out = x * score, nontemporal float4 stores.
// ---------------------------------------------------------------------------
__global__ __launch_bounds__(256) void rgcn_finish_kernel(
    const float2* __restrict__ partial, const float* __restrict__ xr,
    const float* __restrict__ bias, const float* __restrict__ x,
    float* __restrict__ out_x, float* __restrict__ out_score, int n)
{
    __shared__ float ssum[32], scnt[32], sc[32];
    const int t = threadIdx.x;
    const int base = blockIdx.x * 32;

    if (t < 32) { ssum[t] = 0.f; scnt[t] = 0.f; }
    __syncthreads();

    {
        int nl = t & 31;
        int bg = t >> 5;                 // 0..7, covers BPC=32 in 4s
        int node = base + nl;
        float s = 0.f, cN = 0.f;
        if (node < n) {
            int c = node / CHUNK;
            int j = node - c * CHUNK;
            const float2* p = partial + (size_t)c * BPC * CHUNK + j;
            #pragma unroll
            for (int b = 0; b < 4; ++b) {
                float2 v = p[(size_t)(bg * 4 + b) * CHUNK];
                s += v.x; cN += v.y;
            }
        }
        atomicAdd(&ssum[nl], s);
        atomicAdd(&scnt[nl], cN);
    }
    __syncthreads();

    if (t < 32) {
        int node = base + t;
        if (node < n) {
            float m = ssum[t] / fmaxf(scnt[t], 1.0f);
            float v = tanhf(m + xr[node] + bias[0]);
            sc[t] = v;
            out_score[node] = v;
        }
    }
    __syncthreads();

    #pragma unroll
    for (int k = 0; k < 8; ++k) {
        int nl = k * 4 + (t >> 6);       // node local 0..31
        int f4 = t & 63;                 // float4 index in row
        int node = base + nl;
        if (node < n) {
            float s = sc[nl];
            float4 v = *reinterpret_cast<const float4*>(
                           x + (size_t)node * D + f4 * 4);
            v.x *= s; v.y *= s; v.z *= s; v.w *= s;
            f4v vo = {v.x, v.y, v.z, v.w};
            __builtin_nontemporal_store(
                vo, (f4v*)(out_x + (size_t)node * D + f4 * 4));
        }
    }
}

// --------------------- fallback path (scratch in out tail) -----------------
__global__ __launch_bounds__(256) void rgcn_reduce_score_kernel(
    const float2* __restrict__ partial, const float* __restrict__ xr,
    const float* __restrict__ bias, float* __restrict__ score, int n)
{
    int i = blockIdx.x * 256 + threadIdx.x;
    if (i < n) {
        int c = i / CHUNK;
        int j = i - c * CHUNK;
        const float2* p = partial + (size_t)c * BPC * CHUNK + j;
        float s = 0.f, cN = 0.f;
        #pragma unroll 8
        for (int b = 0; b < BPC; ++b) {
            float2 v = p[(size_t)b * CHUNK];
            s += v.x; cN += v.y;
        }
        float m = s / fmaxf(cN, 1.0f);
        score[i] = tanhf(m + xr[i] + bias[0]);
    }
}

__global__ __launch_bounds__(256) void rgcn_scale_kernel(
    const float* __restrict__ x, const float* __restrict__ score,
    float* __restrict__ xo, int n)
{
    int gid = blockIdx.x * 256 + threadIdx.x;
    int node = gid >> 6;
    int f4 = gid & 63;
    if (node < n) {
        float s = score[node];
        float4 v = *reinterpret_cast<const float4*>(
                       x + (size_t)node * D + f4 * 4);
        v.x *= s; v.y *= s; v.z *= s; v.w *= s;
        *reinterpret_cast<float4*>(xo + (size_t)node * D + f4 * 4) = v;
    }
}

extern "C" void kernel_launch(void* const* d_in, const int* in_sizes, int n_in,
                              void* d_out, int out_size, void* d_ws, size_t ws_size,
                              hipStream_t stream)
{
    const float* x    = (const float*)d_in[0];
    const int*   ei   = (const int*)d_in[1];   // (2, E): src then dst
    const int*   et   = (const int*)d_in[2];
    const float* w    = (const float*)d_in[3]; // (R, D, 1) -> flat r*D+d
    const float* root = (const float*)d_in[4]; // (D, 1)    -> flat d
    const float* bias = (const float*)d_in[5];

    const int n = in_sizes[0] / D;   // 50000
    const int e = in_sizes[2];       // 800000

    float* out       = (float*)d_out;
    float* out_x     = out;                       // n*D floats
    float* out_score = out + (size_t)n * D;       // n floats

    const int C = (n + CHUNK - 1) / CHUNK;        // 8 for n=50000
    const int sl = ((((e + BPC - 1) / BPC) + 3) & ~3);  // slice len, mult of 4

    // Scratch: partials (C*BPC*CHUNK float2) | y (16n) | xr (n)
    const size_t part_f = (size_t)C * BPC * CHUNK * 2;   // floats
    const size_t need_f = part_f + (size_t)n * (NREL + 1);
    const bool use_ws = (ws_size >= need_f * sizeof(float));

    float* sb;
    if (use_ws)
        sb = (float*)d_ws;
    else {
        size_t ts = (((size_t)n * D - need_f) & ~(size_t)1);  // 8B-align
        sb = out_x + ts;
    }
    float2* partial = (float2*)sb;
    float*  y  = sb + part_f;
    float*  xr = y + (size_t)n * NREL;

    rgcn_y_kernel<<<dim3((n + 63) / 64), dim3(256), 0, stream>>>(
        x, w, root, y, xr, n);

    rgcn_edge_scan_kernel<<<dim3(C * BPC), dim3(1024), 0, stream>>>(
        ei, ei + e, et, y, partial, e, sl);

    if (use_ws) {
        rgcn_finish_kernel<<<dim3((n + 31) / 32), dim3(256), 0, stream>>>(
            partial, xr, bias, x, out_x, out_score, n);
    } else {
        rgcn_reduce_score_kernel<<<dim3((n + 255) / 256), dim3(256), 0, stream>>>(
            partial, xr, bias, out_score, n);
        rgcn_scale_kernel<<<dim3((int)(((size_t)n * 64 + 255) / 256)), dim3(256), 0, stream>>>(
            x, out_score, out_x, n);
    }
}